// Round 1
// baseline (362.368 us; speedup 1.0000x reference)
//
#include <hip/hip_runtime.h>
#include <math.h>

#define BATCH 8
#define TLEN 2000
#define DIM 512
#define MLEN (TLEN + 1)

// K1: weight[b,t] = sigmoid(dot(feat[b,t,:], W) + bias). One wave per row.
__global__ __launch_bounds__(256) void weight_kernel(
    const float* __restrict__ feat, const float* __restrict__ W,
    const float* __restrict__ bias, float* __restrict__ weight) {
  int gwave = (blockIdx.x * 256 + threadIdx.x) >> 6;   // global wave id = row
  int lane  = threadIdx.x & 63;
  if (gwave >= BATCH * TLEN) return;
  const float4* f4 = (const float4*)feat + (size_t)gwave * (DIM / 4) + lane * 2;
  const float4* w4 = (const float4*)W + lane * 2;
  float4 a0 = f4[0], a1 = f4[1];
  float4 b0 = w4[0], b1 = w4[1];
  float s = a0.x * b0.x + a0.y * b0.y + a0.z * b0.z + a0.w * b0.w +
            a1.x * b1.x + a1.y * b1.y + a1.z * b1.z + a1.w * b1.w;
#pragma unroll
  for (int off = 32; off > 0; off >>= 1) s += __shfl_xor(s, off, 64);
  if (lane == 0) {
    float x = s + bias[0];
    weight[gwave] = 1.0f / (1.0f + expf(-x));
  }
}

// K2: one block per batch. Stage weights in LDS, block-reduce sum -> hlens,
// thread 0 runs the sequential integrate-and-fire scan producing per-t
// (k_t, c0, c1) and per-output-frame contributing ranges [Af, Bl].
__global__ __launch_bounds__(256) void scan_kernel(
    const float* __restrict__ weight, float* __restrict__ hlens_out,
    int* __restrict__ kArr, float* __restrict__ c0A, float* __restrict__ c1A,
    int* __restrict__ Af, int* __restrict__ Bl) {
  int b = blockIdx.x;
  __shared__ float w_s[TLEN];
  __shared__ float red[256];
  __shared__ int Af_s[MLEN];
  __shared__ int Bl_s[MLEN];

  const float* wrow = weight + b * TLEN;
  float local = 0.f;
  for (int t = threadIdx.x; t < TLEN; t += 256) {
    float v = wrow[t];
    w_s[t] = v;
    local += v;
  }
  red[threadIdx.x] = local;
  for (int m = threadIdx.x; m < MLEN; m += 256) {
    Af_s[m] = 0x7fffffff;
    Bl_s[m] = -1;
  }
  __syncthreads();
  for (int s = 128; s > 0; s >>= 1) {
    if (threadIdx.x < s) red[threadIdx.x] += red[threadIdx.x + s];
    __syncthreads();
  }
  if (threadIdx.x == 0) {
    hlens_out[b] = ceilf(red[0]);   // tolerance on this output is ~20: sum order irrelevant
    float acc = 0.f;
    int k = 0;
    int* kp = kArr + b * TLEN;
    float* c0p = c0A + b * TLEN;
    float* c1p = c1A + b * TLEN;
    for (int t = 0; t < TLEN; t++) {
      float w = w_s[t];
      float aw = acc + w;
      bool fire = aw > 1.0f;                     // matches reference: strict >
      float c0 = fire ? (1.0f - acc) : w;        // contribution to frame k
      float c1 = fire ? (aw - 1.0f) : 0.0f;      // contribution to frame k+1
      kp[t] = k; c0p[t] = c0; c1p[t] = c1;
      if (Af_s[k] == 0x7fffffff) Af_s[k] = t;
      Bl_s[k] = t;
      if (fire) {
        int k1 = k + 1;
        if (Af_s[k1] == 0x7fffffff) Af_s[k1] = t;
        Bl_s[k1] = t;
        acc = 0.f;                               // reference resets acc to 0
        k = k1;
      } else {
        acc = aw;
      }
    }
  }
  __syncthreads();
  for (int m = threadIdx.x; m < MLEN; m += 256) {
    Af[(size_t)b * MLEN + m] = Af_s[m];
    Bl[(size_t)b * MLEN + m] = Bl_s[m];
  }
}

// K3: one block per (b, m) output frame; 128 threads x float4 covers D=512.
// Gather the contiguous range of contributing input frames (avg ~2-3).
__global__ __launch_bounds__(128) void gather_kernel(
    const float* __restrict__ feat, const int* __restrict__ kArr,
    const float* __restrict__ c0A, const float* __restrict__ c1A,
    const int* __restrict__ Af, const int* __restrict__ Bl,
    float* __restrict__ out) {
  int bm = blockIdx.x;
  int b = bm / MLEN, m = bm % MLEN;
  int a = Af[(size_t)b * MLEN + m];
  int e = Bl[(size_t)b * MLEN + m];
  float4 acc = {0.f, 0.f, 0.f, 0.f};
  const float4* f4 = (const float4*)feat + (size_t)b * TLEN * (DIM / 4);
  for (int t = a; t <= e; t++) {   // empty when frame untouched (a=INT_MAX, e=-1)
    int kt = kArr[b * TLEN + t];
    float c = (kt == m) ? c0A[b * TLEN + t]
                        : ((kt == m - 1) ? c1A[b * TLEN + t] : 0.0f);
    float4 f = f4[(size_t)t * (DIM / 4) + threadIdx.x];
    acc.x += c * f.x; acc.y += c * f.y; acc.z += c * f.z; acc.w += c * f.w;
  }
  ((float4*)out)[((size_t)b * MLEN + m) * (DIM / 4) + threadIdx.x] = acc;
}

extern "C" void kernel_launch(void* const* d_in, const int* in_sizes, int n_in,
                              void* d_out, int out_size, void* d_ws, size_t ws_size,
                              hipStream_t stream) {
  const float* feat = (const float*)d_in[0];
  // d_in[1] = hlens (unused by the reference computation)
  const float* W    = (const float*)d_in[2];
  const float* bias = (const float*)d_in[3];

  float* out       = (float*)d_out;
  float* feat_new  = out;                                  // B*M*D floats
  float* hlens_out = out + (size_t)BATCH * MLEN * DIM;     // 8 floats (int values)

  char* ws = (char*)d_ws;
  float* weight = (float*)ws;                              // B*T
  int*   kArr   = (int*)(ws + 1 * BATCH * TLEN * 4);
  float* c0A    = (float*)(ws + 2 * BATCH * TLEN * 4);
  float* c1A    = (float*)(ws + 3 * BATCH * TLEN * 4);
  int*   Af     = (int*)(ws + 4 * BATCH * TLEN * 4);
  int*   Bl     = (int*)(ws + 4 * BATCH * TLEN * 4 + BATCH * MLEN * 4);
  // total ws use: ~384 KB

  weight_kernel<<<(BATCH * TLEN) / 4, 256, 0, stream>>>(feat, W, bias, weight);
  scan_kernel<<<BATCH, 256, 0, stream>>>(weight, hlens_out, kArr, c0A, c1A, Af, Bl);
  gather_kernel<<<BATCH * MLEN, 128, 0, stream>>>(feat, kArr, c0A, c1A, Af, Bl, feat_new);
}

// Round 2
// 170.620 us; speedup vs baseline: 2.1238x; 2.1238x over previous
//
#include <hip/hip_runtime.h>
#include <math.h>

#define BATCH 8
#define TLEN 2000
#define DIM 512
#define MLEN (TLEN + 1)

// K1: weight[b,t] = sigmoid(dot(feat[b,t,:], W) + bias). One wave per row.
__global__ __launch_bounds__(256) void weight_kernel(
    const float* __restrict__ feat, const float* __restrict__ W,
    const float* __restrict__ bias, float* __restrict__ weight) {
  int gwave = (blockIdx.x * 256 + threadIdx.x) >> 6;   // global wave id = row
  int lane  = threadIdx.x & 63;
  if (gwave >= BATCH * TLEN) return;
  const float4* f4 = (const float4*)feat + (size_t)gwave * (DIM / 4) + lane * 2;
  const float4* w4 = (const float4*)W + lane * 2;
  float4 a0 = f4[0], a1 = f4[1];
  float4 b0 = w4[0], b1 = w4[1];
  float s = a0.x * b0.x + a0.y * b0.y + a0.z * b0.z + a0.w * b0.w +
            a1.x * b1.x + a1.y * b1.y + a1.z * b1.z + a1.w * b1.w;
#pragma unroll
  for (int off = 32; off > 0; off >>= 1) s += __shfl_xor(s, off, 64);
  if (lane == 0) {
    float x = s + bias[0];
    weight[gwave] = 1.0f / (1.0f + expf(-x));
  }
}

// K2: one block per batch. Minimal-dependent-chain serial scan by thread 0
// (acc -> cmp -> cndmask only; ~12 cyc/iter). w prefetched via double-buffered
// float4 LDS reads. Af/Bl derived IN PARALLEL afterwards from k transitions.
__global__ __launch_bounds__(256) void scan_kernel(
    const float* __restrict__ weight, float* __restrict__ hlens_out,
    int* __restrict__ kArr, float2* __restrict__ c01G,
    int* __restrict__ Af, int* __restrict__ Bl) {
  int b = blockIdx.x;
  __shared__ __align__(16) float w_s[TLEN];
  __shared__ float2 c01_s[TLEN];
  __shared__ unsigned short k_s[TLEN];
  __shared__ int Af_s[MLEN];
  __shared__ int Bl_s[MLEN];
  __shared__ float red[256];
  __shared__ int kfin_s;

  const float* wrow = weight + b * TLEN;
  float local = 0.f;
  for (int t = threadIdx.x; t < TLEN; t += 256) {
    float v = wrow[t];
    w_s[t] = v;
    local += v;
  }
  red[threadIdx.x] = local;
  for (int m = threadIdx.x; m < MLEN; m += 256) {
    Af_s[m] = 0x7fffffff;
    Bl_s[m] = -1;
  }
  __syncthreads();
  for (int s = 128; s > 0; s >>= 1) {
    if (threadIdx.x < s) red[threadIdx.x] += red[threadIdx.x + s];
    __syncthreads();
  }

  if (threadIdx.x == 0) {
    hlens_out[b] = ceilf(red[0]);   // hlens tolerance ~20: sum order irrelevant
    float acc = 0.f;
    int k = 0;
    float4 cur0 = *(const float4*)(w_s);
    float4 cur1 = *(const float4*)(w_s + 4);
    for (int t0 = 0; t0 < TLEN; t0 += 8) {
      float4 nxt0 = cur0, nxt1 = cur1;
      if (t0 + 8 < TLEN) {                     // prefetch next chunk (off-chain)
        nxt0 = *(const float4*)(w_s + t0 + 8);
        nxt1 = *(const float4*)(w_s + t0 + 12);
      }
      float wv[8];
      ((float4*)wv)[0] = cur0;
      ((float4*)wv)[1] = cur1;
#pragma unroll
      for (int j = 0; j < 8; j++) {
        int t = t0 + j;
        float w = wv[j];
        float aw = acc + w;
        bool fire = aw > 1.0f;                 // reference: strict >
        float2 c;
        c.x = fire ? (1.0f - acc) : w;         // contribution to frame k
        c.y = aw - 1.0f;                       // used only at the firing t
        c01_s[t] = c;                          // one ds_write_b64, off-chain
        k_s[t] = (unsigned short)k;            // one ds_write_u16, off-chain
        acc = fire ? 0.0f : aw;                // the only dependent chain
        k += fire;
      }
      cur0 = nxt0; cur1 = nxt1;
    }
    kfin_s = k;
  }
  __syncthreads();

  // Parallel Af/Bl derivation from k transitions.
  int kfin = kfin_s;
  for (int t = threadIdx.x; t < TLEN; t += 256) {
    int kt = k_s[t];
    int kn = (t + 1 < TLEN) ? (int)k_s[t + 1] : kfin;
    if (kn != kt) {            // fire at t
      Af_s[kt + 1] = t;        // firing t is the FIRST contributor to frame kt+1
      Bl_s[kt] = t;            // and the LAST contributor to frame kt
    }
  }
  if (threadIdx.x == 0) {
    Af_s[0] = 0;               // frame 0 always starts at t=0
    Bl_s[kfin] = TLEN - 1;     // last frame always ends at t=T-1
  }
  __syncthreads();

  // Parallel writeout.
  for (int t = threadIdx.x; t < TLEN; t += 256) {
    kArr[b * TLEN + t] = k_s[t];
    c01G[b * TLEN + t] = c01_s[t];
  }
  for (int m = threadIdx.x; m < MLEN; m += 256) {
    Af[(size_t)b * MLEN + m] = Af_s[m];
    Bl[(size_t)b * MLEN + m] = Bl_s[m];
  }
}

// K3: one block per (b, m) output frame; 128 threads x float4 covers D=512.
// Within [Af, Bl], kt == m-1 only at the firing t (take c1), else c0.
__global__ __launch_bounds__(128) void gather_kernel(
    const float* __restrict__ feat, const int* __restrict__ kArr,
    const float2* __restrict__ c01G,
    const int* __restrict__ Af, const int* __restrict__ Bl,
    float* __restrict__ out) {
  int bm = blockIdx.x;
  int b = bm / MLEN, m = bm % MLEN;
  int a = Af[(size_t)b * MLEN + m];
  int e = Bl[(size_t)b * MLEN + m];
  float4 acc = {0.f, 0.f, 0.f, 0.f};
  const float4* f4 = (const float4*)feat + (size_t)b * TLEN * (DIM / 4);
  for (int t = a; t <= e; t++) {   // empty when frame untouched (a=INT_MAX, e=-1)
    float2 c01 = c01G[b * TLEN + t];
    int kt = kArr[b * TLEN + t];
    float c = (kt == m) ? c01.x : c01.y;
    float4 f = f4[(size_t)t * (DIM / 4) + threadIdx.x];
    acc.x += c * f.x; acc.y += c * f.y; acc.z += c * f.z; acc.w += c * f.w;
  }
  ((float4*)out)[((size_t)b * MLEN + m) * (DIM / 4) + threadIdx.x] = acc;
}

extern "C" void kernel_launch(void* const* d_in, const int* in_sizes, int n_in,
                              void* d_out, int out_size, void* d_ws, size_t ws_size,
                              hipStream_t stream) {
  const float* feat = (const float*)d_in[0];
  // d_in[1] = hlens (unused by the reference computation)
  const float* W    = (const float*)d_in[2];
  const float* bias = (const float*)d_in[3];

  float* out       = (float*)d_out;
  float* feat_new  = out;                                  // B*M*D floats
  float* hlens_out = out + (size_t)BATCH * MLEN * DIM;     // 8 floats (int values)

  char* ws = (char*)d_ws;
  float*  weight = (float*)ws;                             // B*T floats  (64000 B)
  int*    kArr   = (int*)(ws + 64000);                     // B*T ints    (64000 B)
  float2* c01    = (float2*)(ws + 128000);                 // B*T float2  (128000 B)
  int*    Af     = (int*)(ws + 256000);                    // B*M ints    (64032 B)
  int*    Bl     = (int*)(ws + 320032);                    // B*M ints    (64032 B)
  // total ws use: ~384 KB

  weight_kernel<<<(BATCH * TLEN) / 4, 256, 0, stream>>>(feat, W, bias, weight);
  scan_kernel<<<BATCH, 256, 0, stream>>>(weight, hlens_out, kArr, c01, Af, Bl);
  gather_kernel<<<BATCH * MLEN, 128, 0, stream>>>(feat, kArr, c01, Af, Bl, feat_new);
}

// Round 3
// 157.252 us; speedup vs baseline: 2.3044x; 1.0850x over previous
//
#include <hip/hip_runtime.h>
#include <math.h>

#define BATCH 8
#define TLEN 2000
#define DIM 512
#define MLEN (TLEN + 1)
#define NW ((TLEN + 63) / 64)   // 32 fire-mask words (TLEN % 64 == 16 tail bits)

// K1: weight[b,t] = sigmoid(dot(feat[b,t,:], W) + bias). One wave per row.
__global__ __launch_bounds__(256) void weight_kernel(
    const float* __restrict__ feat, const float* __restrict__ W,
    const float* __restrict__ bias, float* __restrict__ weight) {
  int gwave = (blockIdx.x * 256 + threadIdx.x) >> 6;   // global wave id = row
  int lane  = threadIdx.x & 63;
  if (gwave >= BATCH * TLEN) return;
  const float4* f4 = (const float4*)feat + (size_t)gwave * (DIM / 4) + lane * 2;
  const float4* w4 = (const float4*)W + lane * 2;
  float4 a0 = f4[0], a1 = f4[1];
  float4 b0 = w4[0], b1 = w4[1];
  float s = a0.x * b0.x + a0.y * b0.y + a0.z * b0.z + a0.w * b0.w +
            a1.x * b1.x + a1.y * b1.y + a1.z * b1.z + a1.w * b1.w;
#pragma unroll
  for (int off = 32; off > 0; off >>= 1) s += __shfl_xor(s, off, 64);
  if (lane == 0) {
    float x = s + bias[0];
    weight[gwave] = 1.0f / (1.0f + expf(-x));
  }
}

// K2: one block per batch. Serial thread produces ONLY a fire bitmask
// (acc -> cmp -> cndmask chain; no in-loop LDS writes except 1 word / 64 t).
// k_t, Af/Bl, c0/c1 all derived in parallel afterwards; c0/c1 recomputed
// per segment with identical sequential fp arithmetic (segments avg ~2).
__global__ __launch_bounds__(256) void scan_kernel(
    const float* __restrict__ weight, float* __restrict__ hlens_out,
    int* __restrict__ kArr, float2* __restrict__ c01G,
    int* __restrict__ Af, int* __restrict__ Bl) {
  int b = blockIdx.x;
  __shared__ __align__(16) float w_s[TLEN];
  __shared__ float2 c01_s[TLEN];
  __shared__ unsigned long long fire_s[NW];
  __shared__ int kpref_s[NW + 1];
  __shared__ int Af_s[MLEN];
  __shared__ int Bl_s[MLEN];
  __shared__ float red[256];

  const float* wrow = weight + b * TLEN;
  float local = 0.f;
  for (int t = threadIdx.x; t < TLEN; t += 256) {
    float v = wrow[t];
    w_s[t] = v;
    local += v;
  }
  red[threadIdx.x] = local;
  for (int m = threadIdx.x; m < MLEN; m += 256) {
    Af_s[m] = 0x7fffffff;
    Bl_s[m] = -1;
  }
  __syncthreads();
  for (int s = 128; s > 0; s >>= 1) {
    if (threadIdx.x < s) red[threadIdx.x] += red[threadIdx.x + s];
    __syncthreads();
  }

  // Phase A: serial fire-mask scan (thread 0). Only LDS ops in flight are
  // the 16-float prefetch reads + one mask-word write per 64 iterations,
  // so the lgkmcnt drain before cur=nxt is cheap.
  if (threadIdx.x == 0) {
    hlens_out[b] = ceilf(red[0]);   // hlens tolerance ~20: sum order irrelevant
    float acc = 0.f;
    unsigned long long mask = 0ull;
    float4 cur0 = ((const float4*)w_s)[0];
    float4 cur1 = ((const float4*)w_s)[1];
    float4 cur2 = ((const float4*)w_s)[2];
    float4 cur3 = ((const float4*)w_s)[3];
    for (int t0 = 0; t0 < TLEN; t0 += 16) {
      float4 n0 = cur0, n1 = cur1, n2 = cur2, n3 = cur3;
      if (t0 + 16 < TLEN) {
        const float4* p = (const float4*)(w_s + t0 + 16);
        n0 = p[0]; n1 = p[1]; n2 = p[2]; n3 = p[3];
      }
      float wv[16];
      ((float4*)wv)[0] = cur0; ((float4*)wv)[1] = cur1;
      ((float4*)wv)[2] = cur2; ((float4*)wv)[3] = cur3;
#pragma unroll
      for (int j = 0; j < 16; j++) {
        float aw = acc + wv[j];
        bool fire = aw > 1.0f;                 // reference: strict >
        mask |= fire ? (1ull << ((t0 + j) & 63)) : 0ull;  // off-chain
        acc = fire ? 0.0f : aw;                // the only dependent chain
      }
      if (((t0 + 16) & 63) == 0) { fire_s[t0 >> 6] = mask; mask = 0ull; }
      cur0 = n0; cur1 = n1; cur2 = n2; cur3 = n3;
    }
    fire_s[NW - 1] = mask;                     // tail word (16 bits)
  }
  __syncthreads();

  // Phase B: exclusive prefix of per-word fire counts (broadcast LDS reads).
  if (threadIdx.x <= NW) {
    int s = 0;
    for (int j = 0; j < (int)threadIdx.x; j++) s += __popcll(fire_s[j]);
    kpref_s[threadIdx.x] = s;
  }
  __syncthreads();
  int kfin = kpref_s[NW];

  // Phase C1: per-t frame index -> kArr (coalesced global write); fire marks.
  for (int t = threadIdx.x; t < TLEN; t += 256) {
    unsigned long long wword = fire_s[t >> 6];
    int bit = t & 63;
    int kt = kpref_s[t >> 6] + __popcll(wword & ((1ull << bit) - 1ull));
    kArr[b * TLEN + t] = kt;
    if ((wword >> bit) & 1ull) {   // fire at t
      Bl_s[kt] = t;                // last contributor to frame kt
      Af_s[kt + 1] = t;            // first contributor to frame kt+1
    }
  }
  // Phase C2: per-segment sequential walk (exact same fp order as reference).
  for (int t = threadIdx.x; t < TLEN; t += 256) {
    bool isStart = (t == 0) || ((fire_s[(t - 1) >> 6] >> ((t - 1) & 63)) & 1ull);
    if (!isStart) continue;
    float acc = 0.f;
    int j = t;
    while (true) {
      float w = w_s[j];
      float aw = acc + w;
      bool fire = aw > 1.0f;
      float2 c;
      c.x = fire ? (1.0f - acc) : w;           // contribution to frame k
      c.y = aw - 1.0f;                         // used only at the firing t
      c01_s[j] = c;
      if (fire || j == TLEN - 1) break;
      acc = aw;
      ++j;
    }
  }
  if (threadIdx.x == 0) {
    Af_s[0] = 0;                 // frame 0 always starts at t=0
    Bl_s[kfin] = TLEN - 1;       // last frame always ends at t=T-1
  }
  __syncthreads();

  // Phase D: coalesced writeout.
  for (int t = threadIdx.x; t < TLEN; t += 256)
    c01G[b * TLEN + t] = c01_s[t];
  for (int m = threadIdx.x; m < MLEN; m += 256) {
    Af[(size_t)b * MLEN + m] = Af_s[m];
    Bl[(size_t)b * MLEN + m] = Bl_s[m];
  }
}

// K3: one block per (b, m) output frame; 128 threads x float4 covers D=512.
// Within [Af, Bl], kt == m-1 only at the firing t (take c1), else c0.
__global__ __launch_bounds__(128) void gather_kernel(
    const float* __restrict__ feat, const int* __restrict__ kArr,
    const float2* __restrict__ c01G,
    const int* __restrict__ Af, const int* __restrict__ Bl,
    float* __restrict__ out) {
  int bm = blockIdx.x;
  int b = bm / MLEN, m = bm % MLEN;
  int a = Af[(size_t)b * MLEN + m];
  int e = Bl[(size_t)b * MLEN + m];
  float4 acc = {0.f, 0.f, 0.f, 0.f};
  const float4* f4 = (const float4*)feat + (size_t)b * TLEN * (DIM / 4);
  for (int t = a; t <= e; t++) {   // empty when frame untouched (a=INT_MAX, e=-1)
    float2 c01 = c01G[b * TLEN + t];
    int kt = kArr[b * TLEN + t];
    float c = (kt == m) ? c01.x : c01.y;
    float4 f = f4[(size_t)t * (DIM / 4) + threadIdx.x];
    acc.x += c * f.x; acc.y += c * f.y; acc.z += c * f.z; acc.w += c * f.w;
  }
  ((float4*)out)[((size_t)b * MLEN + m) * (DIM / 4) + threadIdx.x] = acc;
}

extern "C" void kernel_launch(void* const* d_in, const int* in_sizes, int n_in,
                              void* d_out, int out_size, void* d_ws, size_t ws_size,
                              hipStream_t stream) {
  const float* feat = (const float*)d_in[0];
  // d_in[1] = hlens (unused by the reference computation)
  const float* W    = (const float*)d_in[2];
  const float* bias = (const float*)d_in[3];

  float* out       = (float*)d_out;
  float* feat_new  = out;                                  // B*M*D floats
  float* hlens_out = out + (size_t)BATCH * MLEN * DIM;     // 8 floats (int values)

  char* ws = (char*)d_ws;
  float*  weight = (float*)ws;                             // B*T floats  (64000 B)
  int*    kArr   = (int*)(ws + 64000);                     // B*T ints    (64000 B)
  float2* c01    = (float2*)(ws + 128000);                 // B*T float2  (128000 B)
  int*    Af     = (int*)(ws + 256000);                    // B*M ints    (64032 B)
  int*    Bl     = (int*)(ws + 320032);                    // B*M ints    (64032 B)
  // total ws use: ~384 KB

  weight_kernel<<<(BATCH * TLEN) / 4, 256, 0, stream>>>(feat, W, bias, weight);
  scan_kernel<<<BATCH, 256, 0, stream>>>(weight, hlens_out, kArr, c01, Af, Bl);
  gather_kernel<<<BATCH * MLEN, 128, 0, stream>>>(feat, kArr, c01, Af, Bl, feat_new);
}

// Round 4
// 121.170 us; speedup vs baseline: 2.9906x; 1.2978x over previous
//
#include <hip/hip_runtime.h>
#include <math.h>

#define BATCH 8
#define TLEN 2000
#define DIM 512
#define MLEN (TLEN + 1)
#define NLVL 11              // 2^11 = 2048 > max fires (2000)

// K1: weight[b,t] = sigmoid(dot(feat[b,t,:], W) + bias). One wave per row.
__global__ __launch_bounds__(256) void weight_kernel(
    const float* __restrict__ feat, const float* __restrict__ W,
    const float* __restrict__ bias, float* __restrict__ weight) {
  int gwave = (blockIdx.x * 256 + threadIdx.x) >> 6;   // global wave id = row
  int lane  = threadIdx.x & 63;
  if (gwave >= BATCH * TLEN) return;
  const float4* f4 = (const float4*)feat + (size_t)gwave * (DIM / 4) + lane * 2;
  const float4* w4 = (const float4*)W + lane * 2;
  float4 a0 = f4[0], a1 = f4[1];
  float4 b0 = w4[0], b1 = w4[1];
  float s = a0.x * b0.x + a0.y * b0.y + a0.z * b0.z + a0.w * b0.w +
            a1.x * b1.x + a1.y * b1.y + a1.z * b1.z + a1.w * b1.w;
#pragma unroll
  for (int off = 32; off > 0; off >>= 1) s += __shfl_xor(s, off, 64);
  if (lane == 0) {
    float x = s + bias[0];
    weight[gwave] = 1.0f / (1.0f + expf(-x));
  }
}

// K2: fully parallel integrate-and-fire via prefix sums + binary lifting.
// acc resets to 0 on fire => fires are the orbit of jump(s) = min t>s with
// S_t - S_s > 1. No serial section at all.
__global__ __launch_bounds__(256) void scan_kernel(
    const float* __restrict__ weight, float* __restrict__ hlens_out,
    int* __restrict__ kArr, float2* __restrict__ c01G,
    int* __restrict__ Af, int* __restrict__ Bl) {
  int b = blockIdx.x;
  int tid = threadIdx.x;
  __shared__ float w_s[TLEN];
  __shared__ float S_s[TLEN];
  __shared__ float tsum[256];
  __shared__ unsigned short G_s[NLVL][MLEN];   // 11 * 2001 * 2B = 44 KB
  __shared__ unsigned short F_s[MLEN];         // fire positions
  __shared__ int t0_s, K_s;

  // --- Phase 1: load weights (chunked float4) + local scan + block scan ---
  const float* wrow = weight + b * TLEN;
  int base = tid * 8;
  float loc[8];
  float run = 0.f;
  if (base + 8 <= TLEN) {
    float4 v0 = *(const float4*)(wrow + base);
    float4 v1 = *(const float4*)(wrow + base + 4);
    float wv[8] = {v0.x, v0.y, v0.z, v0.w, v1.x, v1.y, v1.z, v1.w};
#pragma unroll
    for (int j = 0; j < 8; j++) {
      w_s[base + j] = wv[j];
      run += wv[j];
      loc[j] = run;
    }
  }
  tsum[tid] = (base + 8 <= TLEN) ? run : 0.f;   // TLEN=2000: threads 0..249 active
  __syncthreads();
  // Hillis-Steele inclusive scan over 256 partials
  for (int d = 1; d < 256; d <<= 1) {
    float v = (tid >= d) ? tsum[tid - d] : 0.f;
    __syncthreads();
    tsum[tid] += v;
    __syncthreads();
  }
  float offs = (tid > 0) ? tsum[tid - 1] : 0.f;
  if (base + 8 <= TLEN) {
#pragma unroll
    for (int j = 0; j < 8; j++) S_s[base + j] = offs + loc[j];
  }
  if (tid == 0) {
    hlens_out[b] = ceilf(tsum[255]);  // hlens tol ~20: sum order irrelevant
  }
  __syncthreads();

  // --- Phase 2: G_0[s] = min t>s with S_t > S_s + 1 (batched binary search) ---
  {
    int l[8], r[8];
    float tgt[8];
#pragma unroll
    for (int it = 0; it < 8; it++) {
      int s = tid + it * 256;
      if (s <= TLEN && s < TLEN - 1) {
        l[it] = s + 1; r[it] = TLEN; tgt[it] = S_s[s] + 1.0f;
      } else {
        l[it] = TLEN; r[it] = TLEN; tgt[it] = 0.f;
      }
    }
    for (int step = 0; step < NLVL; step++) {
#pragma unroll
      for (int it = 0; it < 8; it++) {
        if (l[it] < r[it]) {
          int mid = (l[it] + r[it]) >> 1;
          float v = S_s[mid];                 // 8 independent LDS reads/step
          if (v > tgt[it]) r[it] = mid; else l[it] = mid + 1;
        }
      }
    }
#pragma unroll
    for (int it = 0; it < 8; it++) {
      int s = tid + it * 256;
      if (s <= TLEN) G_s[0][s] = (unsigned short)l[it];
    }
  }
  if (tid == 0) {      // first fire: min t with S_t > 1
    int l = 0, r = TLEN;
    while (l < r) { int mid = (l + r) >> 1; if (S_s[mid] > 1.0f) r = mid; else l = mid + 1; }
    t0_s = l;
  }
  __syncthreads();

  // --- Phase 3: binary lifting G_{j+1}[s] = G_j[G_j[s]] ---
  for (int j = 0; j < NLVL - 1; j++) {
    int g1[8];
#pragma unroll
    for (int it = 0; it < 8; it++) {
      int s = tid + it * 256;
      g1[it] = (s <= TLEN) ? (int)G_s[j][s] : TLEN;
    }
    int g2[8];
#pragma unroll
    for (int it = 0; it < 8; it++) g2[it] = (int)G_s[j][g1[it]];
    __syncthreads();    // (writes go to level j+1, reads were level j; barrier for safety/order)
#pragma unroll
    for (int it = 0; it < 8; it++) {
      int s = tid + it * 256;
      if (s <= TLEN) G_s[j + 1][s] = (unsigned short)g2[it];
    }
    __syncthreads();
  }

  // --- Phase 4: fire positions F[k] = jump^k(t0) via bit composition ---
  {
    int t0 = t0_s;
    int t[8];
    int kk[8];
#pragma unroll
    for (int it = 0; it < 8; it++) { kk[it] = tid + it * 256; t[it] = t0; }
    for (int j = 0; j < NLVL; j++) {
#pragma unroll
      for (int it = 0; it < 8; it++) {
        if (kk[it] <= TLEN && ((kk[it] >> j) & 1)) t[it] = (int)G_s[j][t[it]];
      }
    }
#pragma unroll
    for (int it = 0; it < 8; it++)
      if (kk[it] <= TLEN) F_s[kk[it]] = (unsigned short)t[it];
  }
  __syncthreads();

  // --- Phase 5: K = number of fires (smallest k with F[k]==T) ---
  for (int k = tid; k <= TLEN; k += 256) {
    if ((int)F_s[k] == TLEN && (k == 0 || (int)F_s[k - 1] < TLEN)) K_s = k;
  }
  __syncthreads();
  int K = K_s;

  // --- Phase 6: kArr + c0/c1 (batched binary search over F), coalesced out ---
  {
    int l[8], r[8];
#pragma unroll
    for (int it = 0; it < 8; it++) {
      int t = tid + it * 256;
      if (t < TLEN) { l[it] = 0; r[it] = K; } else { l[it] = 0; r[it] = 0; }
    }
    for (int step = 0; step < NLVL; step++) {
#pragma unroll
      for (int it = 0; it < 8; it++) {
        if (l[it] < r[it]) {
          int t = tid + it * 256;
          int mid = (l[it] + r[it]) >> 1;
          int v = (int)F_s[mid];
          if (v >= t) r[it] = mid; else l[it] = mid + 1;
        }
      }
    }
#pragma unroll
    for (int it = 0; it < 8; it++) {
      int t = tid + it * 256;
      if (t >= TLEN) continue;
      int k = l[it];                         // #fires strictly before t
      bool fire = ((int)F_s[k] == t);        // (k<=K; F[k]==t implies k<K)
      int s = (k == 0) ? 0 : (int)F_s[k - 1] + 1;
      float Ssm1 = (s == 0) ? 0.f : S_s[s - 1];
      float accb = ((t == 0) ? 0.f : S_s[t - 1]) - Ssm1;
      float c0 = fire ? (1.0f - accb) : w_s[t];
      float c1 = (S_s[t] - Ssm1) - 1.0f;     // only read at firing t
      kArr[b * TLEN + t] = k;
      c01G[b * TLEN + t] = float2{c0, c1};
    }
  }

  // --- Phase 7: Af/Bl straight from F (coalesced global writes) ---
  for (int m = tid; m < MLEN; m += 256) {
    int af, bl;
    if (m == 0) af = 0;
    else if (m <= K) af = (int)F_s[m - 1];   // firing t of fire m-1 feeds frame m
    else af = 0x7fffffff;
    if (m < K) bl = (int)F_s[m];             // frame m ends at its own fire
    else if (m == K) bl = TLEN - 1;          // trailing partial frame
    else bl = -1;
    Af[(size_t)b * MLEN + m] = af;
    Bl[(size_t)b * MLEN + m] = bl;
  }
}

// K3: one block per (b, m) output frame; 128 threads x float4 covers D=512.
// Within [Af, Bl], kt == m-1 only at the firing t (take c1), else c0.
__global__ __launch_bounds__(128) void gather_kernel(
    const float* __restrict__ feat, const int* __restrict__ kArr,
    const float2* __restrict__ c01G,
    const int* __restrict__ Af, const int* __restrict__ Bl,
    float* __restrict__ out) {
  int bm = blockIdx.x;
  int b = bm / MLEN, m = bm % MLEN;
  int a = Af[(size_t)b * MLEN + m];
  int e = Bl[(size_t)b * MLEN + m];
  float4 acc = {0.f, 0.f, 0.f, 0.f};
  const float4* f4 = (const float4*)feat + (size_t)b * TLEN * (DIM / 4);
  for (int t = a; t <= e; t++) {   // empty when frame untouched (a=INT_MAX, e=-1)
    float2 c01 = c01G[b * TLEN + t];
    int kt = kArr[b * TLEN + t];
    float c = (kt == m) ? c01.x : c01.y;
    float4 f = f4[(size_t)t * (DIM / 4) + threadIdx.x];
    acc.x += c * f.x; acc.y += c * f.y; acc.z += c * f.z; acc.w += c * f.w;
  }
  ((float4*)out)[((size_t)b * MLEN + m) * (DIM / 4) + threadIdx.x] = acc;
}

extern "C" void kernel_launch(void* const* d_in, const int* in_sizes, int n_in,
                              void* d_out, int out_size, void* d_ws, size_t ws_size,
                              hipStream_t stream) {
  const float* feat = (const float*)d_in[0];
  // d_in[1] = hlens (unused by the reference computation)
  const float* W    = (const float*)d_in[2];
  const float* bias = (const float*)d_in[3];

  float* out       = (float*)d_out;
  float* feat_new  = out;                                  // B*M*D floats
  float* hlens_out = out + (size_t)BATCH * MLEN * DIM;     // 8 floats (int values)

  char* ws = (char*)d_ws;
  float*  weight = (float*)ws;                             // B*T floats  (64000 B)
  int*    kArr   = (int*)(ws + 64000);                     // B*T ints    (64000 B)
  float2* c01    = (float2*)(ws + 128000);                 // B*T float2  (128000 B)
  int*    Af     = (int*)(ws + 256000);                    // B*M ints    (64032 B)
  int*    Bl     = (int*)(ws + 320032);                    // B*M ints    (64032 B)
  // total ws use: ~384 KB

  weight_kernel<<<(BATCH * TLEN) / 4, 256, 0, stream>>>(feat, W, bias, weight);
  scan_kernel<<<BATCH, 256, 0, stream>>>(weight, hlens_out, kArr, c01, Af, Bl);
  gather_kernel<<<BATCH * MLEN, 128, 0, stream>>>(feat, kArr, c01, Af, Bl, feat_new);
}

// Round 5
// 101.208 us; speedup vs baseline: 3.5804x; 1.1972x over previous
//
#include <hip/hip_runtime.h>
#include <math.h>

#define BATCH 8
#define TLEN 2000
#define DIM 512
#define MLEN (TLEN + 1)
#define NTH 1024             // scan block size
#define NWORD 32             // fire bitmask words (2000 bits)
#define MAXLVL 11

// K1: weight[b,t] = sigmoid(dot(feat[b,t,:], W) + bias). One wave per row.
__global__ __launch_bounds__(256) void weight_kernel(
    const float* __restrict__ feat, const float* __restrict__ W,
    const float* __restrict__ bias, float* __restrict__ weight) {
  int gwave = (blockIdx.x * 256 + threadIdx.x) >> 6;   // global wave id = row
  int lane  = threadIdx.x & 63;
  if (gwave >= BATCH * TLEN) return;
  const float4* f4 = (const float4*)feat + (size_t)gwave * (DIM / 4) + lane * 2;
  const float4* w4 = (const float4*)W + lane * 2;
  float4 a0 = f4[0], a1 = f4[1];
  float4 b0 = w4[0], b1 = w4[1];
  float s = a0.x * b0.x + a0.y * b0.y + a0.z * b0.z + a0.w * b0.w +
            a1.x * b1.x + a1.y * b1.y + a1.z * b1.z + a1.w * b1.w;
#pragma unroll
  for (int off = 32; off > 0; off >>= 1) s += __shfl_xor(s, off, 64);
  if (lane == 0) {
    float x = s + bias[0];
    weight[gwave] = 1.0f / (1.0f + expf(-x));
  }
}

// K2: fully parallel integrate-and-fire. Prefix sum (wave shuffles) ->
// next-fire table G0 (batched binary search) -> orbit via binary lifting
// with fused F-extension and early exit -> fire bitmask -> c0/c1 and
// packed per-frame ranges AB. No kArr, no per-t rank search.
__global__ __launch_bounds__(NTH) void scan_kernel(
    const float* __restrict__ weight, float* __restrict__ hlens_out,
    float2* __restrict__ c01G, int2* __restrict__ AB) {
  int b = blockIdx.x;
  int tid = threadIdx.x;
  int lane = tid & 63, wid = tid >> 6;

  __shared__ float w_s[TLEN];
  __shared__ float S_s[TLEN];
  __shared__ float wtot[16];
  __shared__ unsigned short Ga_s[MLEN];    // ping
  __shared__ unsigned short Gb_s[MLEN];    // pong
  __shared__ unsigned short F_s[2048];     // fire positions (K <= 1000)
  __shared__ unsigned long long mask_s[NWORD];
  __shared__ int lastw_s[NWORD];           // last fire index < 64*w (or -1)
  __shared__ int done_lv[MAXLVL];
  __shared__ int K_s;

  // --- Phase 1: load + prefix sum via wave shuffles (2 elems/thread) ---
  const float* wrow = weight + b * TLEN;
  int base = tid * 2;
  float w0 = 0.f, w1 = 0.f;
  if (base < TLEN) {                        // base <= 1998, base+1 < TLEN
    float2 v = *(const float2*)(wrow + base);
    w0 = v.x; w1 = v.y;
  }
  float mysum = w0 + w1;
  float sc = mysum;
#pragma unroll
  for (int d = 1; d < 64; d <<= 1) {
    float o = __shfl_up(sc, d, 64);
    if (lane >= d) sc += o;
  }
  if (lane == 63) wtot[wid] = sc;
  if (tid < NWORD) mask_s[tid] = 0ull;      // pre-zero fire mask
  if (tid < MAXLVL) done_lv[tid] = 1;       // per-level done flags
  __syncthreads();
  float woff = 0.f;
  for (int j = 0; j < wid; j++) woff += wtot[j];   // broadcast reads
  float excl = woff + (sc - mysum);
  if (base < TLEN) {
    w_s[base] = w0; w_s[base + 1] = w1;
    S_s[base] = excl + w0;
    S_s[base + 1] = excl + w0 + w1;
  }
  if (tid == 0) {
    float tot = 0.f;
    for (int j = 0; j < 16; j++) tot += wtot[j];
    hlens_out[b] = ceilf(tot);              // hlens tol ~20: order irrelevant
  }
  __syncthreads();

  // --- Phase 2: G0[s] = min t>s with S[t] > S[s]+1; t0 = min t, S[t] > 1 ---
  {
    // jobs: j0 = s(tid), j1 = s(tid+1024) if valid, j2 (tid 0 only) = t0
    int l0 = tid + 1, r0 = TLEN;  float tg0 = S_s[tid] + 1.0f;
    int s1v = tid + 1024;
    bool has1 = (s1v < TLEN);
    int l1 = has1 ? s1v + 1 : TLEN, r1 = TLEN;
    float tg1 = has1 ? S_s[s1v] + 1.0f : 0.f;
    bool has2 = (tid == 0);
    int l2 = 0, r2 = has2 ? TLEN : 0;
#pragma unroll
    for (int step = 0; step < MAXLVL; step++) {
      if (l0 < r0) { int m = (l0 + r0) >> 1; if (S_s[m] > tg0) r0 = m; else l0 = m + 1; }
      if (l1 < r1) { int m = (l1 + r1) >> 1; if (S_s[m] > tg1) r1 = m; else l1 = m + 1; }
      if (l2 < r2) { int m = (l2 + r2) >> 1; if (S_s[m] > 1.0f) r2 = m; else l2 = m + 1; }
    }
    Ga_s[tid] = (unsigned short)l0;
    if (has1) Ga_s[s1v] = (unsigned short)l1;
    F_s[tid] = (unsigned short)TLEN;
    F_s[tid + 1024] = (unsigned short)TLEN;
    if (tid == 0) {
      Ga_s[TLEN] = (unsigned short)TLEN;    // sentinel self-loop
      F_s[0] = (unsigned short)l2;          // first fire (TLEN if none)
    }
  }
  __syncthreads();

  // --- Phase 3: lifting + fused orbit doubling, 1 barrier/level, early exit ---
  {
    unsigned short* cur = Ga_s;
    unsigned short* nxt = Gb_s;
    int flen = 1;
    for (int lvl = 0; lvl < MAXLVL; lvl++) {
      int s0 = tid, s1v = tid + 1024;
      int g20 = (int)cur[cur[s0]];
      int g21 = (s1v <= TLEN) ? (int)cur[cur[s1v]] : TLEN;
      // orbit extension: F[flen+i] = jump^flen(F[i])
      int i0 = tid, i1 = tid + 1024;
      int nv0 = -1, nv1 = -1;
      if (i0 < flen) nv0 = (int)cur[F_s[i0]];
      if (i1 < flen) nv1 = (int)cur[F_s[i1]];
      nxt[s0] = (unsigned short)g20;
      if (s1v <= TLEN) nxt[s1v] = (unsigned short)g21;
      if (i0 < flen) { F_s[flen + i0] = (unsigned short)nv0; if (nv0 < TLEN) done_lv[lvl] = 0; }
      if (i1 < flen) { F_s[flen + i1] = (unsigned short)nv1; if (nv1 < TLEN) done_lv[lvl] = 0; }
      __syncthreads();
      flen <<= 1;
      unsigned short* t = cur; cur = nxt; nxt = t;
      if (done_lv[lvl]) break;              // uniform: no new fires added
    }
  }

  // --- Phase 4: fire bitmask scatter ---
  {
    int t0v = (int)F_s[tid];
    int t1v = (int)F_s[tid + 1024];
    if (t0v < TLEN) atomicOr(&mask_s[t0v >> 6], 1ull << (t0v & 63));
    if (t1v < TLEN) atomicOr(&mask_s[t1v >> 6], 1ull << (t1v & 63));
  }
  __syncthreads();
  if (tid == 0) {                           // 32-word mini-pass: lastw + K
    int last = -1, cnt = 0;
    for (int wd = 0; wd < NWORD; wd++) {
      lastw_s[wd] = last;
      unsigned long long m = mask_s[wd];
      cnt += __popcll(m);
      if (m) last = wd * 64 + 63 - __clzll(m);
    }
    K_s = cnt;
  }
  __syncthreads();
  int K = K_s;

  // --- Phase 5: c0/c1 per t (coalesced writes) ---
#pragma unroll
  for (int it = 0; it < 2; it++) {
    int t = tid + it * 1024;
    if (t >= TLEN) continue;
    unsigned long long wd = mask_s[t >> 6];
    int bit = t & 63;
    unsigned long long below = wd & ((1ull << bit) - 1ull);
    int pf = below ? ((t & ~63) + 63 - __clzll(below)) : lastw_s[t >> 6];
    float Spf = (pf >= 0) ? S_s[pf] : 0.f;
    float accb = ((t > 0) ? S_s[t - 1] : 0.f) - Spf;   // acc before step t
    bool fire = (wd >> bit) & 1ull;
    float c0 = fire ? (1.0f - accb) : w_s[t];
    float c1 = (S_s[t] - Spf) - 1.0f;                  // read only at firing t
    c01G[b * TLEN + t] = float2{c0, c1};
  }

  // --- Phase 6: packed per-frame ranges AB[m] = {Af, Bl} ---
#pragma unroll
  for (int it = 0; it < 2; it++) {
    int m = tid + it * 1024;
    if (m >= MLEN) continue;
    int af = (m == 0) ? 0 : ((m <= K) ? (int)F_s[m - 1] : 0x7fffffff);
    int bl = (m < K) ? (int)F_s[m] : ((m == K) ? TLEN - 1 : -1);
    AB[(size_t)b * MLEN + m] = int2{af, bl};
  }
}

// K3: one block per (b, m) frame; 128 threads x float4 covers D=512.
// Within [a, e]: only t==a (for m>0) takes the leftover c1; all else c0.
__global__ __launch_bounds__(128) void gather_kernel(
    const float* __restrict__ feat, const float2* __restrict__ c01G,
    const int2* __restrict__ AB, float* __restrict__ out) {
  int bm = blockIdx.x;
  int b = bm / MLEN, m = bm % MLEN;
  int2 ab = AB[(size_t)bm];
  int a = ab.x, e = ab.y;
  int afire = (m > 0) ? a : -1;             // t that contributes c1
  float4 acc = {0.f, 0.f, 0.f, 0.f};
  const float4* f4 = (const float4*)feat + (size_t)b * TLEN * (DIM / 4);
  const float2* crow = c01G + b * TLEN;
  for (int t = a; t <= e; t++) {            // empty when frame untouched
    float2 c01 = crow[t];
    float c = (t == afire) ? c01.y : c01.x;
    float4 f = f4[(size_t)t * (DIM / 4) + threadIdx.x];
    acc.x += c * f.x; acc.y += c * f.y; acc.z += c * f.z; acc.w += c * f.w;
  }
  ((float4*)out)[(size_t)bm * (DIM / 4) + threadIdx.x] = acc;
}

extern "C" void kernel_launch(void* const* d_in, const int* in_sizes, int n_in,
                              void* d_out, int out_size, void* d_ws, size_t ws_size,
                              hipStream_t stream) {
  const float* feat = (const float*)d_in[0];
  // d_in[1] = hlens (unused by the reference computation)
  const float* W    = (const float*)d_in[2];
  const float* bias = (const float*)d_in[3];

  float* out       = (float*)d_out;
  float* feat_new  = out;                                  // B*M*D floats
  float* hlens_out = out + (size_t)BATCH * MLEN * DIM;     // 8 floats (int values)

  char* ws = (char*)d_ws;
  float*  weight = (float*)ws;                             // B*T floats   (64000 B)
  float2* c01    = (float2*)(ws + 64000);                  // B*T float2  (128000 B)
  int2*   AB     = (int2*)(ws + 192000);                   // B*M int2    (128064 B)

  weight_kernel<<<(BATCH * TLEN) / 4, 256, 0, stream>>>(feat, W, bias, weight);
  scan_kernel<<<BATCH, NTH, 0, stream>>>(weight, hlens_out, c01, AB);
  gather_kernel<<<BATCH * MLEN, 128, 0, stream>>>(feat, c01, AB, feat_new);
}